// Round 2
// baseline (442.123 us; speedup 1.0000x reference)
//
#include <hip/hip_runtime.h>

#define T_STEPS 512
#define BT 16          // batches per block (one 16-col MFMA tile, batch = l15)
#define XSTRIDE 524    // padded x row stride (floats); %32==12 -> 2-way read aliasing (free)
#define HSTRIDE 72     // padded h row stride (shorts); 144B rows, 16B aligned

typedef __attribute__((ext_vector_type(8))) short bf16x8;
typedef __attribute__((ext_vector_type(4))) float f32x4;
typedef __attribute__((ext_vector_type(2))) unsigned u32x2;

__device__ __forceinline__ short f2bf(float f) {
    union { float f; unsigned u; } v; v.f = f;
    unsigned r = v.u + 0x7fffu + ((v.u >> 16) & 1u);   // RNE
    return (short)(r >> 16);
}
__device__ __forceinline__ float bf2f(short s) {
    union { float f; unsigned u; } v;
    v.u = ((unsigned)(unsigned short)s) << 16;
    return v.f;
}
__device__ __forceinline__ float ubits(unsigned u) {
    union { unsigned u; float f; } v; v.u = u; return v.f;
}
__device__ __forceinline__ float exp2_fast(float x) {
#if __has_builtin(__builtin_amdgcn_exp2f)
    return __builtin_amdgcn_exp2f(x);
#else
    return __expf(x * 0.69314718056f);
#endif
}

#define L2E 1.44269504089f   // log2(e)
#define C2  2.88539008178f   // 2*log2(e)

__global__ __launch_bounds__(512, 2) void lstm_persist(
    const float* __restrict__ x,      // [B, T] (IN=1 folded)
    const float* __restrict__ W_ih,   // [256]
    const float* __restrict__ W_hh,   // [256,64]
    const float* __restrict__ b_ih,   // [256]
    const float* __restrict__ b_hh,   // [256]
    const float* __restrict__ W_fc,   // [64]
    const float* __restrict__ b_fc,   // [1]
    float* __restrict__ out)          // [B]
{
    __shared__ __align__(16) float x_lds[BT * XSTRIDE];      // 33.5 KB
    __shared__ __align__(16) short hbuf[2][2][BT][HSTRIDE];  // 18.4 KB [buf][hi/lo][b][k]
    __shared__ __align__(16) float pbuf[4][4][256];          // 16 KB [ks][g][lane*4+r] f32 partials

    const int tid  = threadIdx.x;
    const int wav  = tid >> 6;        // 0..7
    const int ks   = wav & 3;         // k-slice: k in [16*ks, 16*ks+16)
    const bool MAIN = (wav < 4);      // waves 0-3 main, 4-7 correction
    const int lane = tid & 63;
    const int l15  = lane & 15;       // batch index (output col)
    const int quad = lane >> 4;       // 0..3
    const int b0   = blockIdx.x * BT;

    // ---- stage x[b0..b0+15][0..511] into LDS (coalesced float4, 512 threads) ----
    {
        const float* xg = x + (size_t)b0 * T_STEPS;
        #pragma unroll
        for (int i = 0; i < 4; ++i) {
            int f4 = tid + i * 512;        // 0..2047 float4 chunks
            int b  = f4 >> 7;              // 128 float4 per row
            int t4 = f4 & 127;
            float4 v = reinterpret_cast<const float4*>(xg + (size_t)b * T_STEPS)[t4];
            reinterpret_cast<float4*>(&x_lds[b * XSTRIDE + t4 * 4])[0] = v;
        }
    }
    // ---- zero h buffer 0 (hi+lo) ----
    {
        short* p = &hbuf[0][0][0][0];
        for (int i = tid; i < 2 * 2 * BT * HSTRIDE; i += 512) p[i] = 0;
    }

    // ---- per-lane resident W_hh fragments (split bf16 of SCALED weights) ----
    // Gate scale folded into weights: i,f,o rows by -log2e; g rows by -2*log2e.
    // acc then directly yields exp2 args: ei=exp2(acc_i) etc.
    // A-frag: lane holds A[m=l15][k=quad*8+j] = W'[g*64+ks*16+l15][kh*32+quad*8+j]
    const float scg[4] = { -L2E, -L2E, -C2, -L2E };
    bf16x8 Whi[4][2], Wlo[4][2];
    float bias[4][4], wih[4][4];
    #pragma unroll
    for (int g = 0; g < 4; ++g) {
        int na = g * 64 + ks * 16 + l15;
        #pragma unroll
        for (int kh = 0; kh < 2; ++kh) {
            const float* wr = W_hh + na * 64 + kh * 32 + quad * 8;
            bf16x8 hi, lo;
            #pragma unroll
            for (int j = 0; j < 8; ++j) {
                float w = wr[j] * scg[g];
                short h16 = f2bf(w);
                hi[j] = h16;
                lo[j] = f2bf(w - bf2f(h16));
            }
            Whi[g][kh] = hi;
            Wlo[g][kh] = lo;
        }
        // D layout: col = l15 (batch), row = quad*4 + r ->
        // lane owns gate g, k_hidden = ks*16 + quad*4 + r, batch l15.
        #pragma unroll
        for (int r = 0; r < 4; ++r) {
            int n = g * 64 + ks * 16 + quad * 4 + r;
            bias[g][r] = scg[g] * (b_ih[n] + b_hh[n]);
            wih[g][r]  = scg[g] * W_ih[n];
        }
    }

    float ct[4] = {0.f, 0.f, 0.f, 0.f};   // cell state in the 2*log2e-scaled domain
    const int hoff = l15 * HSTRIDE + quad * 8;
    const int woff = l15 * HSTRIDE + ks * 16 + quad * 4;
    const float* xrow = &x_lds[l15 * XSTRIDE];
    float* pmy = &pbuf[ks][0][lane * 4];   // gate stride = 256 floats; conflict-floor b128s

    __syncthreads();

    for (int t = 0; t < T_STEPS; ++t) {
        const int rb = t & 1, wb = rb ^ 1;
        const short* hhi = &hbuf[rb][0][0][0];
        const short* hlo = &hbuf[rb][1][0][0];

        f32x4 acc[4];
        // ---------------- phase 1 ----------------
        if (MAIN) {
            bf16x8 bhi0 = *reinterpret_cast<const bf16x8*>(hhi + hoff);
            bf16x8 bhi1 = *reinterpret_cast<const bf16x8*>(hhi + hoff + 32);
            float xv = xrow[t];
            #pragma unroll
            for (int g = 0; g < 4; ++g) {
                #pragma unroll
                for (int r = 0; r < 4; ++r)
                    acc[g][r] = fmaf(wih[g][r], xv, bias[g][r]);
                acc[g] = __builtin_amdgcn_mfma_f32_16x16x32_bf16(Whi[g][0], bhi0, acc[g], 0, 0, 0);
                acc[g] = __builtin_amdgcn_mfma_f32_16x16x32_bf16(Whi[g][1], bhi1, acc[g], 0, 0, 0);
            }
        } else {
            bf16x8 bhi0 = *reinterpret_cast<const bf16x8*>(hhi + hoff);
            bf16x8 bhi1 = *reinterpret_cast<const bf16x8*>(hhi + hoff + 32);
            bf16x8 blo0 = *reinterpret_cast<const bf16x8*>(hlo + hoff);
            bf16x8 blo1 = *reinterpret_cast<const bf16x8*>(hlo + hoff + 32);
            #pragma unroll
            for (int g = 0; g < 4; ++g) {
                f32x4 pa = {0.f, 0.f, 0.f, 0.f};
                f32x4 pb = {0.f, 0.f, 0.f, 0.f};
                pa = __builtin_amdgcn_mfma_f32_16x16x32_bf16(Whi[g][0], blo0, pa, 0, 0, 0);
                pa = __builtin_amdgcn_mfma_f32_16x16x32_bf16(Wlo[g][0], bhi0, pa, 0, 0, 0);
                pb = __builtin_amdgcn_mfma_f32_16x16x32_bf16(Whi[g][1], blo1, pb, 0, 0, 0);
                pb = __builtin_amdgcn_mfma_f32_16x16x32_bf16(Wlo[g][1], bhi1, pb, 0, 0, 0);
                f32x4 s = pa + pb;
                *reinterpret_cast<f32x4*>(pmy + g * 256) = s;
            }
        }
        __syncthreads();   // corr partials visible
        // ---------------- phase 2 (main only; corr waves free the SIMD) ----------------
        if (MAIN) {
            #pragma unroll
            for (int g = 0; g < 4; ++g) {
                f32x4 p = *reinterpret_cast<const f32x4*>(pmy + g * 256);
                acc[g] += p;
            }
            // activations; acc is already the exp2 argument (scaled domain)
            float hv[4];
            #pragma unroll
            for (int r = 0; r < 4; ++r) {
                float ai = acc[0][r], af = acc[1][r], ag = acc[2][r], ao = acc[3][r];
                float ei = exp2_fast(ai);
                float ef = exp2_fast(af);
                float eg = exp2_fast(-fabsf(ag));   // <= 1
                float eo = exp2_fast(ao);
                float Ai = 1.0f + ei, Af = 1.0f + ef, Ag = 1.0f + eg, Ao = 1.0f + eo;
                float tg = copysignf(fmaf(-C2, eg, C2), -ag);   // 2log2e * (1-eg), sign(g)
                float P  = Ai * Ag;
                float num = fmaf(ct[r], P, tg * Af);
                float cn  = num * __builtin_amdgcn_rcpf(P * Af); // scaled cell state
                ct[r] = cn;
                float ec = exp2_fast(-fabsf(cn));   // <= 1
                float tc = copysignf(1.0f - ec, cn);
                hv[r] = tc * __builtin_amdgcn_rcpf(Ao * (1.0f + ec));  // real-unit h
            }

            // pack 4 consecutive k as bf16 pairs (HW RNE) + exact lo residuals
            unsigned hi0, hi1, lo0, lo1;
            asm("v_cvt_pk_bf16_f32 %0, %1, %2" : "=v"(hi0) : "v"(hv[0]), "v"(hv[1]));
            asm("v_cvt_pk_bf16_f32 %0, %1, %2" : "=v"(hi1) : "v"(hv[2]), "v"(hv[3]));
            float l0f = hv[0] - ubits(hi0 << 16);
            float l1f = hv[1] - ubits(hi0 & 0xffff0000u);
            float l2f = hv[2] - ubits(hi1 << 16);
            float l3f = hv[3] - ubits(hi1 & 0xffff0000u);
            asm("v_cvt_pk_bf16_f32 %0, %1, %2" : "=v"(lo0) : "v"(l0f), "v"(l1f));
            asm("v_cvt_pk_bf16_f32 %0, %1, %2" : "=v"(lo1) : "v"(l2f), "v"(l3f));
            u32x2 vhi = {hi0, hi1};
            u32x2 vlo = {lo0, lo1};
            *reinterpret_cast<u32x2*>(&hbuf[wb][0][0][0] + woff) = vhi;
            *reinterpret_cast<u32x2*>(&hbuf[wb][1][0][0] + woff) = vlo;
        }
        __syncthreads();   // h(t+1) visible; protects pbuf + rb overwrite
    }

    // ---- final FC: out[b] = sum_k h[b][k]*W_fc[k] + b_fc  (h = buf 0 after t=511) ----
    if (tid < 16) {
        int b = tid;
        float s = b_fc[0];
        #pragma unroll 4
        for (int k = 0; k < 64; ++k) {
            float hv = bf2f(hbuf[0][0][b][k]) + bf2f(hbuf[0][1][b][k]);
            s += hv * W_fc[k];
        }
        out[b0 + b] = s;
    }
}

extern "C" void kernel_launch(void* const* d_in, const int* in_sizes, int n_in,
                              void* d_out, int out_size, void* d_ws, size_t ws_size,
                              hipStream_t stream) {
    const float* x    = (const float*)d_in[0];
    const float* W_ih = (const float*)d_in[1];
    const float* W_hh = (const float*)d_in[2];
    const float* b_ih = (const float*)d_in[3];
    const float* b_hh = (const float*)d_in[4];
    const float* W_fc = (const float*)d_in[5];
    const float* b_fc = (const float*)d_in[6];
    float* out = (float*)d_out;
    const int B = in_sizes[0] / T_STEPS;   // 4096
    lstm_persist<<<dim3(B / BT), dim3(512), 0, stream>>>(
        x, W_ih, W_hh, b_ih, b_hh, W_fc, b_fc, out);
}

// Round 3
// 396.514 us; speedup vs baseline: 1.1150x; 1.1150x over previous
//
#include <hip/hip_runtime.h>

#define T_STEPS 512
#define BT 16          // batches per block (one 16-col MFMA tile, batch = l15)
#define XSTRIDE 524    // padded x row stride (floats)
#define HSTRIDE 72     // padded h row stride (shorts); 144B rows, 16B aligned

typedef __attribute__((ext_vector_type(8))) short bf16x8;
typedef __attribute__((ext_vector_type(4))) float f32x4;
typedef __attribute__((ext_vector_type(2))) unsigned u32x2;

__device__ __forceinline__ short f2bf(float f) {
    union { float f; unsigned u; } v; v.f = f;
    unsigned r = v.u + 0x7fffu + ((v.u >> 16) & 1u);   // RNE
    return (short)(r >> 16);
}
__device__ __forceinline__ float bf2f(short s) {
    union { float f; unsigned u; } v;
    v.u = ((unsigned)(unsigned short)s) << 16;
    return v.f;
}
__device__ __forceinline__ float ubits(unsigned u) {
    union { unsigned u; float f; } v; v.u = u; return v.f;
}
__device__ __forceinline__ float exp2_fast(float x) {
#if __has_builtin(__builtin_amdgcn_exp2f)
    return __builtin_amdgcn_exp2f(x);
#else
    return __expf(x * 0.69314718056f);
#endif
}

#define L2E 1.44269504089f   // log2(e)
#define C2  2.88539008178f   // 2*log2(e)

__global__ __launch_bounds__(256, 1) void lstm_persist(
    const float* __restrict__ x,      // [B, T] (IN=1 folded)
    const float* __restrict__ W_ih,   // [256]
    const float* __restrict__ W_hh,   // [256,64]
    const float* __restrict__ b_ih,   // [256]
    const float* __restrict__ b_hh,   // [256]
    const float* __restrict__ W_fc,   // [64]
    const float* __restrict__ b_fc,   // [1]
    float* __restrict__ out)          // [B]
{
    __shared__ __align__(16) float x_lds[BT * XSTRIDE];
    __shared__ __align__(16) short hbuf[2][2][BT][HSTRIDE]; // [buf][hi/lo][b][k]

    const int tid  = threadIdx.x;
    const int wave = tid >> 6;     // 0..3  -> k-slice: k in [16w, 16w+16)
    const int lane = tid & 63;
    const int l15  = lane & 15;    // batch index (output col)
    const int quad = lane >> 4;    // 0..3
    const int b0   = blockIdx.x * BT;

    // ---- stage x[b0..b0+15][0..511] into LDS (coalesced float4) ----
    {
        const float* xg = x + (size_t)b0 * T_STEPS;
        #pragma unroll
        for (int i = 0; i < 8; ++i) {
            int f4 = tid + i * 256;        // 0..2047 float4 chunks
            int b  = f4 >> 7;              // 128 float4 per row
            int t4 = f4 & 127;
            float4 v = reinterpret_cast<const float4*>(xg + (size_t)b * T_STEPS)[t4];
            reinterpret_cast<float4*>(&x_lds[b * XSTRIDE + t4 * 4])[0] = v;
        }
    }
    // ---- zero h buffer 0 (hi+lo) ----
    {
        short* p = &hbuf[0][0][0][0];
        for (int i = tid; i < 2 * BT * HSTRIDE; i += 256) p[i] = 0;
    }

    // ---- per-lane resident W_hh fragments (split bf16 of SCALED weights) ----
    // Gate scales folded in: i,f,o rows by -log2e; g rows by -2*log2e.
    // acc then directly yields exp2 args (ei = exp2(acc_i), etc).
    // A-frag: lane holds A[m=l15][k=quad*8+j] = W'[g*64+wave*16+l15][kh*32+quad*8+j]
    const float scg[4] = { -L2E, -L2E, -C2, -L2E };
    bf16x8 Whi[4][2], Wlo[4][2];
    float bias[4][4], wih[4][4];
    #pragma unroll
    for (int g = 0; g < 4; ++g) {
        int na = g * 64 + wave * 16 + l15;
        #pragma unroll
        for (int kh = 0; kh < 2; ++kh) {
            const float* wr = W_hh + na * 64 + kh * 32 + quad * 8;
            bf16x8 hi, lo;
            #pragma unroll
            for (int j = 0; j < 8; ++j) {
                float w = wr[j] * scg[g];
                short h16 = f2bf(w);
                hi[j] = h16;
                lo[j] = f2bf(w - bf2f(h16));
            }
            Whi[g][kh] = hi;
            Wlo[g][kh] = lo;
        }
        // D layout: col = l15 (batch), row = quad*4 + r ->
        // lane owns gate g, k_hidden = wave*16 + quad*4 + r, batch l15.
        #pragma unroll
        for (int r = 0; r < 4; ++r) {
            int n = g * 64 + wave * 16 + quad * 4 + r;
            bias[g][r] = scg[g] * (b_ih[n] + b_hh[n]);
            wih[g][r]  = scg[g] * W_ih[n];
        }
    }

    float ct[4] = {0.f, 0.f, 0.f, 0.f};   // cell state, scaled by 2*log2e
    const int hoff = l15 * HSTRIDE + quad * 8;
    const int woff = l15 * HSTRIDE + wave * 16 + quad * 4;
    const float* xrow = &x_lds[l15 * XSTRIDE];

    __syncthreads();

    // init for t=0 precomputed (x is h-independent): un-roots MFMA chain from x load
    float initv[4][4];
    {
        float xv = xrow[0];
        #pragma unroll
        for (int g = 0; g < 4; ++g)
            #pragma unroll
            for (int r = 0; r < 4; ++r)
                initv[g][r] = fmaf(wih[g][r], xv, bias[g][r]);
    }

    for (int t = 0; t < T_STEPS; ++t) {
        const int rb = t & 1, wb = rb ^ 1;
        const short* hhi = &hbuf[rb][0][0][0];
        const short* hlo = &hbuf[rb][1][0][0];

        // issue kh=0 reads first: acc chain depends only on these two
        bf16x8 bhi0 = *reinterpret_cast<const bf16x8*>(hhi + hoff);
        bf16x8 blo0 = *reinterpret_cast<const bf16x8*>(hlo + hoff);
        bf16x8 bhi1 = *reinterpret_cast<const bf16x8*>(hhi + hoff + 32);
        bf16x8 blo1 = *reinterpret_cast<const bf16x8*>(hlo + hoff + 32);

        // split accumulators: kh=0 terms -> acc, kh=1 terms -> accb (chain 6 -> 3)
        f32x4 acc[4], accb[4];
        #pragma unroll
        for (int g = 0; g < 4; ++g) {
            #pragma unroll
            for (int r = 0; r < 4; ++r) acc[g][r] = initv[g][r];
            accb[g] = (f32x4){0.f, 0.f, 0.f, 0.f};
        }
        #pragma unroll
        for (int g = 0; g < 4; ++g) {
            acc[g]  = __builtin_amdgcn_mfma_f32_16x16x32_bf16(Whi[g][0], bhi0, acc[g],  0, 0, 0);
            acc[g]  = __builtin_amdgcn_mfma_f32_16x16x32_bf16(Whi[g][0], blo0, acc[g],  0, 0, 0);
            acc[g]  = __builtin_amdgcn_mfma_f32_16x16x32_bf16(Wlo[g][0], bhi0, acc[g],  0, 0, 0);
            accb[g] = __builtin_amdgcn_mfma_f32_16x16x32_bf16(Whi[g][1], bhi1, accb[g], 0, 0, 0);
            accb[g] = __builtin_amdgcn_mfma_f32_16x16x32_bf16(Whi[g][1], blo1, accb[g], 0, 0, 0);
            accb[g] = __builtin_amdgcn_mfma_f32_16x16x32_bf16(Wlo[g][1], bhi1, accb[g], 0, 0, 0);
        }
        #pragma unroll
        for (int g = 0; g < 4; ++g) acc[g] += accb[g];

        // activations in scaled domain: acc IS the exp2 argument
        float hv[4];
        #pragma unroll
        for (int r = 0; r < 4; ++r) {
            float ai = acc[0][r], af = acc[1][r], ag = acc[2][r], ao = acc[3][r];
            float ei = exp2_fast(ai);
            float ef = exp2_fast(af);
            float eg = exp2_fast(-fabsf(ag));   // <= 1
            float eo = exp2_fast(ao);
            float Ai = 1.0f + ei, Af = 1.0f + ef, Ag = 1.0f + eg, Ao = 1.0f + eo;
            float P   = Ai * Ag;
            float PAF = P * Af;
            float rP  = __builtin_amdgcn_rcpf(PAF);          // starts early, || with num
            float tg  = copysignf(fmaf(-C2, eg, C2), -ag);   // 2log2e*(1-eg), sign(g)
            float num = fmaf(ct[r], P, tg * Af);
            float cn  = num * rP;                            // scaled cell state
            ct[r] = cn;
            float ec = exp2_fast(-fabsf(cn));   // <= 1
            float tc = copysignf(1.0f - ec, cn);
            hv[r] = tc * __builtin_amdgcn_rcpf(Ao * (1.0f + ec));  // real-unit h
        }

        // pack 4 consecutive k as bf16 pairs (HW RNE) + exact lo residuals
        unsigned hi0, hi1, lo0, lo1;
        asm("v_cvt_pk_bf16_f32 %0, %1, %2" : "=v"(hi0) : "v"(hv[0]), "v"(hv[1]));
        asm("v_cvt_pk_bf16_f32 %0, %1, %2" : "=v"(hi1) : "v"(hv[2]), "v"(hv[3]));
        float l0f = hv[0] - ubits(hi0 << 16);
        float l1f = hv[1] - ubits(hi0 & 0xffff0000u);
        float l2f = hv[2] - ubits(hi1 << 16);
        float l3f = hv[3] - ubits(hi1 & 0xffff0000u);
        asm("v_cvt_pk_bf16_f32 %0, %1, %2" : "=v"(lo0) : "v"(l0f), "v"(l1f));
        asm("v_cvt_pk_bf16_f32 %0, %1, %2" : "=v"(lo1) : "v"(l2f), "v"(l3f));
        u32x2 vhi = {hi0, hi1};
        u32x2 vlo = {lo0, lo1};
        *reinterpret_cast<u32x2*>(&hbuf[wb][0][0][0] + woff) = vhi;
        *reinterpret_cast<u32x2*>(&hbuf[wb][1][0][0] + woff) = vlo;

        // prefetch next step's x and precompute the acc-chain root (fills write/barrier tail)
        {
            float xn = xrow[t + 1];   // t=511 reads in-bounds pad; result unused
            #pragma unroll
            for (int g = 0; g < 4; ++g)
                #pragma unroll
                for (int r = 0; r < 4; ++r)
                    initv[g][r] = fmaf(wih[g][r], xn, bias[g][r]);
        }

        __syncthreads();   // h(t+1) visible; also protects next step's overwrite of rb
    }

    // ---- final FC: out[b] = sum_k h[b][k]*W_fc[k] + b_fc  (h = buf 0 after t=511) ----
    if (tid < 16) {
        int b = tid;
        float s = b_fc[0];
        #pragma unroll 4
        for (int k = 0; k < 64; ++k) {
            float hv = bf2f(hbuf[0][0][b][k]) + bf2f(hbuf[0][1][b][k]);
            s += hv * W_fc[k];
        }
        out[b0 + b] = s;
    }
}

extern "C" void kernel_launch(void* const* d_in, const int* in_sizes, int n_in,
                              void* d_out, int out_size, void* d_ws, size_t ws_size,
                              hipStream_t stream) {
    const float* x    = (const float*)d_in[0];
    const float* W_ih = (const float*)d_in[1];
    const float* W_hh = (const float*)d_in[2];
    const float* b_ih = (const float*)d_in[3];
    const float* b_hh = (const float*)d_in[4];
    const float* W_fc = (const float*)d_in[5];
    const float* b_fc = (const float*)d_in[6];
    float* out = (float*)d_out;
    const int B = in_sizes[0] / T_STEPS;   // 4096
    lstm_persist<<<dim3(B / BT), dim3(256), 0, stream>>>(
        x, W_ih, W_hh, b_ih, b_hh, W_fc, b_fc, out);
}

// Round 4
// 360.653 us; speedup vs baseline: 1.2259x; 1.0994x over previous
//
#include <hip/hip_runtime.h>

#define T_STEPS 512
#define BT 16          // batches per block (one 16-col MFMA tile, batch = l15)
#define XSTRIDE 524    // padded x row stride (floats)
#define HSTRIDE 72     // padded h row stride (shorts); 144B rows, 16B aligned

typedef __attribute__((ext_vector_type(8))) short bf16x8;
typedef __attribute__((ext_vector_type(4))) float f32x4;

__device__ __forceinline__ short f2bf(float f) {
    union { float f; unsigned u; } v; v.f = f;
    unsigned r = v.u + 0x7fffu + ((v.u >> 16) & 1u);   // RNE
    return (short)(r >> 16);
}
__device__ __forceinline__ float bf2f(short s) {
    union { float f; unsigned u; } v;
    v.u = ((unsigned)(unsigned short)s) << 16;
    return v.f;
}
__device__ __forceinline__ float ubits(unsigned u) {
    union { unsigned u; float f; } v; v.u = u; return v.f;
}
__device__ __forceinline__ float exp2_fast(float x) {
#if __has_builtin(__builtin_amdgcn_exp2f)
    return __builtin_amdgcn_exp2f(x);
#else
    return __expf(x * 0.69314718056f);
#endif
}

#define L2E 1.44269504089f   // log2(e)
#define C2  2.88539008178f   // 2*log2(e)

__global__ __launch_bounds__(256, 1) void lstm_persist(
    const float* __restrict__ x,      // [B, T] (IN=1 folded)
    const float* __restrict__ W_ih,   // [256]
    const float* __restrict__ W_hh,   // [256,64]
    const float* __restrict__ b_ih,   // [256]
    const float* __restrict__ b_hh,   // [256]
    const float* __restrict__ W_fc,   // [64]
    const float* __restrict__ b_fc,   // [1]
    float* __restrict__ out)          // [B]
{
    __shared__ __align__(16) float x_lds[BT * XSTRIDE];
    __shared__ __align__(16) short hbuf[2][2][BT][HSTRIDE]; // [buf][hi/lo][b][k]

    const int tid  = threadIdx.x;
    const int wave = tid >> 6;     // 0..3  -> k-slice: k in [16w, 16w+16)
    const int lane = tid & 63;
    const int l15  = lane & 15;    // batch index (output col)
    const int quad = lane >> 4;    // 0..3
    const int b0   = blockIdx.x * BT;

    // ---- stage x[b0..b0+15][0..511] into LDS (coalesced float4) ----
    {
        const float* xg = x + (size_t)b0 * T_STEPS;
        #pragma unroll
        for (int i = 0; i < 8; ++i) {
            int f4 = tid + i * 256;        // 0..2047 float4 chunks
            int b  = f4 >> 7;              // 128 float4 per row
            int t4 = f4 & 127;
            float4 v = reinterpret_cast<const float4*>(xg + (size_t)b * T_STEPS)[t4];
            reinterpret_cast<float4*>(&x_lds[b * XSTRIDE + t4 * 4])[0] = v;
        }
    }
    // ---- zero h buffer 0 (hi+lo) ----
    {
        short* p = &hbuf[0][0][0][0];
        for (int i = tid; i < 2 * BT * HSTRIDE; i += 256) p[i] = 0;
    }

    // ---- per-lane resident W_hh fragments (split bf16 of SCALED weights) ----
    // Gate scales folded in: i,f,o rows by -log2e; g rows by -2*log2e.
    // acc then directly yields exp2 args (ei = exp2(acc_i), etc).
    const float scg[4] = { -L2E, -L2E, -C2, -L2E };
    bf16x8 Whi[4][2], Wlo[4][2];
    f32x4 bias4[4], wih4[4];
    #pragma unroll
    for (int g = 0; g < 4; ++g) {
        int na = g * 64 + wave * 16 + l15;
        #pragma unroll
        for (int kh = 0; kh < 2; ++kh) {
            const float* wr = W_hh + na * 64 + kh * 32 + quad * 8;
            bf16x8 hi, lo;
            #pragma unroll
            for (int j = 0; j < 8; ++j) {
                float w = wr[j] * scg[g];
                short h16 = f2bf(w);
                hi[j] = h16;
                lo[j] = f2bf(w - bf2f(h16));
            }
            Whi[g][kh] = hi;
            Wlo[g][kh] = lo;
        }
        // D layout: col = l15 (batch), row = quad*4 + r ->
        // lane owns gate g, k_hidden = wave*16 + quad*4 + r, batch l15.
        #pragma unroll
        for (int r = 0; r < 4; ++r) {
            int n = g * 64 + wave * 16 + quad * 4 + r;
            bias4[g][r] = scg[g] * (b_ih[n] + b_hh[n]);
            wih4[g][r]  = scg[g] * W_ih[n];
        }
    }

    float ct[4] = {0.f, 0.f, 0.f, 0.f};   // cell state, scaled by 2*log2e
    const int hoff = l15 * HSTRIDE + quad * 8;
    const int woff = l15 * HSTRIDE + wave * 16 + quad * 4;   // shorts, even
    unsigned* whi32 = reinterpret_cast<unsigned*>(&hbuf[0][0][0][0]);  // indexed per-buffer below
    const float* xrow = &x_lds[l15 * XSTRIDE];

    __syncthreads();

    // init for t=0 precomputed (x is h-independent): un-roots MFMA chain from x load
    f32x4 iv[4];
    {
        float xv = xrow[0];
        #pragma unroll
        for (int g = 0; g < 4; ++g)
            #pragma unroll
            for (int r = 0; r < 4; ++r)
                iv[g][r] = fmaf(wih4[g][r], xv, bias4[g][r]);
    }

    #pragma unroll 2
    for (int t = 0; t < T_STEPS; ++t) {
        const int rb = t & 1, wb = rb ^ 1;
        const short* hhi = &hbuf[rb][0][0][0];
        const short* hlo = &hbuf[rb][1][0][0];

        bf16x8 bhi0 = *reinterpret_cast<const bf16x8*>(hhi + hoff);
        bf16x8 bhi1 = *reinterpret_cast<const bf16x8*>(hhi + hoff + 32);
        bf16x8 blo0 = *reinterpret_cast<const bf16x8*>(hlo + hoff);
        bf16x8 blo1 = *reinterpret_cast<const bf16x8*>(hlo + hoff + 32);

        // R1's verified 6-term order, C-op seeded directly from prefetched iv
        f32x4 acc[4];
        #pragma unroll
        for (int g = 0; g < 4; ++g) {
            acc[g] = __builtin_amdgcn_mfma_f32_16x16x32_bf16(Whi[g][0], bhi0, iv[g], 0, 0, 0);
            acc[g] = __builtin_amdgcn_mfma_f32_16x16x32_bf16(Whi[g][1], bhi1, acc[g], 0, 0, 0);
            acc[g] = __builtin_amdgcn_mfma_f32_16x16x32_bf16(Whi[g][0], blo0, acc[g], 0, 0, 0);
            acc[g] = __builtin_amdgcn_mfma_f32_16x16x32_bf16(Whi[g][1], blo1, acc[g], 0, 0, 0);
            acc[g] = __builtin_amdgcn_mfma_f32_16x16x32_bf16(Wlo[g][0], bhi0, acc[g], 0, 0, 0);
            acc[g] = __builtin_amdgcn_mfma_f32_16x16x32_bf16(Wlo[g][1], bhi1, acc[g], 0, 0, 0);
        }

        // activations in scaled domain: acc IS the exp2 argument.
        // signed-eg (|ag|<=25 -> eg<=2^25, safe); clamped signed-ec (exact saturation).
        float hv[4];
        #pragma unroll
        for (int r = 0; r < 4; ++r) {
            float ai = acc[0][r], af = acc[1][r], ag = acc[2][r], ao = acc[3][r];
            float ei = exp2_fast(ai);
            float ef = exp2_fast(af);
            float eg = exp2_fast(ag);                       // signed, no fabs
            float eo = exp2_fast(ao);
            float Ai = 1.0f + ei, Af = 1.0f + ef, Ag = 1.0f + eg, Ao = 1.0f + eo;
            float P   = Ai * Ag;
            float PAF = P * Af;
            float rP  = __builtin_amdgcn_rcpf(PAF);         // || with num path
            float tg  = fmaf(-C2, eg, C2);                  // C2*(1-eg), sign built in
            float num = fmaf(ct[r], P, tg * Af);
            float cn  = num * rP;                           // scaled cell state
            ct[r] = cn;
            float ec = exp2_fast(fminf(-cn, 40.0f));        // exp2(-cn), clamped (safe)
            float tc = 1.0f - ec;                           // sign built in
            hv[r] = tc * __builtin_amdgcn_rcpf(Ao * (1.0f + ec));  // real-unit h
        }

        // per-pair bf16 pack (HW RNE) + exact lo residuals; 4x ds_write_b32
        unsigned* whi = reinterpret_cast<unsigned*>(&hbuf[wb][0][0][0]);
        unsigned* wlo = reinterpret_cast<unsigned*>(&hbuf[wb][1][0][0]);
        unsigned hi01, hi23, lo01, lo23;
        asm("v_cvt_pk_bf16_f32 %0, %1, %2" : "=v"(hi01) : "v"(hv[0]), "v"(hv[1]));
        whi[(woff >> 1) + 0] = hi01;
        asm("v_cvt_pk_bf16_f32 %0, %1, %2" : "=v"(hi23) : "v"(hv[2]), "v"(hv[3]));
        whi[(woff >> 1) + 1] = hi23;
        float l0f = hv[0] - ubits(hi01 << 16);
        float l1f = hv[1] - ubits(hi01 & 0xffff0000u);
        asm("v_cvt_pk_bf16_f32 %0, %1, %2" : "=v"(lo01) : "v"(l0f), "v"(l1f));
        wlo[(woff >> 1) + 0] = lo01;
        float l2f = hv[2] - ubits(hi23 << 16);
        float l3f = hv[3] - ubits(hi23 & 0xffff0000u);
        asm("v_cvt_pk_bf16_f32 %0, %1, %2" : "=v"(lo23) : "v"(l2f), "v"(l3f));
        wlo[(woff >> 1) + 1] = lo23;

        // prefetch next step's x and precompute next acc-chain root (off-path)
        {
            float xn = xrow[t + 1];   // t=511 reads in-bounds pad; result unused
            #pragma unroll
            for (int g = 0; g < 4; ++g)
                #pragma unroll
                for (int r = 0; r < 4; ++r)
                    iv[g][r] = fmaf(wih4[g][r], xn, bias4[g][r]);
        }

        __syncthreads();   // h(t+1) visible; also protects next step's overwrite of rb
    }

    // ---- final FC: out[b] = sum_k h[b][k]*W_fc[k] + b_fc  (h = buf 0 after t=511) ----
    if (tid < 16) {
        int b = tid;
        float s = b_fc[0];
        #pragma unroll 4
        for (int k = 0; k < 64; ++k) {
            float hv = bf2f(hbuf[0][0][b][k]) + bf2f(hbuf[0][1][b][k]);
            s += hv * W_fc[k];
        }
        out[b0 + b] = s;
    }
    (void)whi32;
}

extern "C" void kernel_launch(void* const* d_in, const int* in_sizes, int n_in,
                              void* d_out, int out_size, void* d_ws, size_t ws_size,
                              hipStream_t stream) {
    const float* x    = (const float*)d_in[0];
    const float* W_ih = (const float*)d_in[1];
    const float* W_hh = (const float*)d_in[2];
    const float* b_ih = (const float*)d_in[3];
    const float* b_hh = (const float*)d_in[4];
    const float* W_fc = (const float*)d_in[5];
    const float* b_fc = (const float*)d_in[6];
    float* out = (float*)d_out;
    const int B = in_sizes[0] / T_STEPS;   // 4096
    lstm_persist<<<dim3(B / BT), dim3(256), 0, stream>>>(
        x, W_ih, W_hh, b_ih, b_hh, W_fc, b_fc, out);
}

// Round 5
// 357.800 us; speedup vs baseline: 1.2357x; 1.0080x over previous
//
#include <hip/hip_runtime.h>

#define T_STEPS 512
#define BT 16          // batches per block (one 16-col MFMA tile, batch = l15)
#define XSTRIDE 524    // padded x row stride (floats)
#define HSTRIDE 72     // padded h row stride (shorts); 144B rows, 16B aligned

typedef __attribute__((ext_vector_type(8))) short bf16x8;
typedef __attribute__((ext_vector_type(4))) float f32x4;

__device__ __forceinline__ short f2bf(float f) {
    union { float f; unsigned u; } v; v.f = f;
    unsigned r = v.u + 0x7fffu + ((v.u >> 16) & 1u);   // RNE
    return (short)(r >> 16);
}
__device__ __forceinline__ float bf2f(short s) {
    union { float f; unsigned u; } v;
    v.u = ((unsigned)(unsigned short)s) << 16;
    return v.f;
}
__device__ __forceinline__ float ubits(unsigned u) {
    union { unsigned u; float f; } v; v.u = u; return v.f;
}
__device__ __forceinline__ float exp2_fast(float x) {
#if __has_builtin(__builtin_amdgcn_exp2f)
    return __builtin_amdgcn_exp2f(x);
#else
    return __expf(x * 0.69314718056f);
#endif
}

#define L2E 1.44269504089f   // log2(e)
#define C2  2.88539008178f   // 2*log2(e)

__global__ __launch_bounds__(256, 1) void lstm_persist(
    const float* __restrict__ x,      // [B, T] (IN=1 folded)
    const float* __restrict__ W_ih,   // [256]
    const float* __restrict__ W_hh,   // [256,64]
    const float* __restrict__ b_ih,   // [256]
    const float* __restrict__ b_hh,   // [256]
    const float* __restrict__ W_fc,   // [64]
    const float* __restrict__ b_fc,   // [1]
    float* __restrict__ out)          // [B]
{
    __shared__ __align__(16) float x_lds[BT * XSTRIDE];
    __shared__ __align__(16) short hbuf[2][2][BT][HSTRIDE]; // [buf][hi/lo][b][k]

    const int tid  = threadIdx.x;
    const int wave = tid >> 6;     // 0..3  -> k-slice: k in [16w, 16w+16)
    const int lane = tid & 63;
    const int l15  = lane & 15;    // batch index (output col)
    const int quad = lane >> 4;    // 0..3
    const int b0   = blockIdx.x * BT;

    // ---- stage x[b0..b0+15][0..511] into LDS (coalesced float4) ----
    {
        const float* xg = x + (size_t)b0 * T_STEPS;
        #pragma unroll
        for (int i = 0; i < 8; ++i) {
            int f4 = tid + i * 256;        // 0..2047 float4 chunks
            int b  = f4 >> 7;              // 128 float4 per row
            int t4 = f4 & 127;
            float4 v = reinterpret_cast<const float4*>(xg + (size_t)b * T_STEPS)[t4];
            reinterpret_cast<float4*>(&x_lds[b * XSTRIDE + t4 * 4])[0] = v;
        }
    }
    // ---- zero h buffer 0 (hi+lo) ----
    {
        short* p = &hbuf[0][0][0][0];
        for (int i = tid; i < 2 * BT * HSTRIDE; i += 256) p[i] = 0;
    }

    // ---- per-lane resident W_hh fragments (split bf16 of SCALED weights) ----
    // Gate scales folded in: i,f,o rows by -log2e; g rows by -2*log2e.
    // acc then directly yields exp2 args (ei = exp2(acc_i), etc).
    const float scg[4] = { -L2E, -L2E, -C2, -L2E };
    bf16x8 Whi[4][2], Wlo[4][2];
    f32x4 bias4[4], wih4[4];
    #pragma unroll
    for (int g = 0; g < 4; ++g) {
        int na = g * 64 + wave * 16 + l15;
        #pragma unroll
        for (int kh = 0; kh < 2; ++kh) {
            const float* wr = W_hh + na * 64 + kh * 32 + quad * 8;
            bf16x8 hi, lo;
            #pragma unroll
            for (int j = 0; j < 8; ++j) {
                float w = wr[j] * scg[g];
                short h16 = f2bf(w);
                hi[j] = h16;
                lo[j] = f2bf(w - bf2f(h16));
            }
            Whi[g][kh] = hi;
            Wlo[g][kh] = lo;
        }
        // D layout: col = l15 (batch), row = quad*4 + r ->
        // lane owns gate g, k_hidden = wave*16 + quad*4 + r, batch l15.
        #pragma unroll
        for (int r = 0; r < 4; ++r) {
            int n = g * 64 + wave * 16 + quad * 4 + r;
            bias4[g][r] = scg[g] * (b_ih[n] + b_hh[n]);
            wih4[g][r]  = scg[g] * W_ih[n];
        }
    }

    f32x4 ct4 = {0.f, 0.f, 0.f, 0.f};   // cell state, scaled by 2*log2e
    const int hoff = l15 * HSTRIDE + quad * 8;
    const int woff = l15 * HSTRIDE + wave * 16 + quad * 4;   // shorts, even
    const float* xrow = &x_lds[l15 * XSTRIDE];

    const f32x4 vone  = {1.f, 1.f, 1.f, 1.f};
    const f32x4 vnC2  = {-C2, -C2, -C2, -C2};
    const f32x4 vC2   = {C2, C2, C2, C2};
    const f32x4 v40   = {40.f, 40.f, 40.f, 40.f};

    __syncthreads();

    // init for t=0 precomputed (x is h-independent): un-roots MFMA chain from x load
    f32x4 iv[4];
    {
        float xv = xrow[0];
        f32x4 xv4 = {xv, xv, xv, xv};
        #pragma unroll
        for (int g = 0; g < 4; ++g)
            iv[g] = __builtin_elementwise_fma(wih4[g], xv4, bias4[g]);
    }

    #pragma unroll 2
    for (int t = 0; t < T_STEPS; ++t) {
        const int rb = t & 1, wb = rb ^ 1;
        const short* hhi = &hbuf[rb][0][0][0];
        const short* hlo = &hbuf[rb][1][0][0];

        // issue all LDS reads up front (h fragments + next-step x)
        bf16x8 bhi0 = *reinterpret_cast<const bf16x8*>(hhi + hoff);
        bf16x8 bhi1 = *reinterpret_cast<const bf16x8*>(hhi + hoff + 32);
        bf16x8 blo0 = *reinterpret_cast<const bf16x8*>(hlo + hoff);
        bf16x8 blo1 = *reinterpret_cast<const bf16x8*>(hlo + hoff + 32);
        float xn = xrow[t + 1];   // t=511 reads in-bounds pad; result unused

        // verified 6-term order, C-op seeded directly from prefetched iv
        f32x4 acc[4];
        #pragma unroll
        for (int g = 0; g < 4; ++g) {
            acc[g] = __builtin_amdgcn_mfma_f32_16x16x32_bf16(Whi[g][0], bhi0, iv[g], 0, 0, 0);
            acc[g] = __builtin_amdgcn_mfma_f32_16x16x32_bf16(Whi[g][1], bhi1, acc[g], 0, 0, 0);
            acc[g] = __builtin_amdgcn_mfma_f32_16x16x32_bf16(Whi[g][0], blo0, acc[g], 0, 0, 0);
            acc[g] = __builtin_amdgcn_mfma_f32_16x16x32_bf16(Whi[g][1], blo1, acc[g], 0, 0, 0);
            acc[g] = __builtin_amdgcn_mfma_f32_16x16x32_bf16(Wlo[g][0], bhi0, acc[g], 0, 0, 0);
            acc[g] = __builtin_amdgcn_mfma_f32_16x16x32_bf16(Wlo[g][1], bhi1, acc[g], 0, 0, 0);
        }

        // next-step iv prefetch issues in the MFMA-latency shadow (packed fp32)
        {
            f32x4 xn4 = {xn, xn, xn, xn};
            #pragma unroll
            for (int g = 0; g < 4; ++g)
                iv[g] = __builtin_elementwise_fma(wih4[g], xn4, bias4[g]);
        }

        // activations in scaled domain, vectorized f32x4 (v_pk_* for non-trans math).
        // signed-eg (|ag|<=26 -> eg<=2^26, safe); clamped signed-ec (exact saturation).
        f32x4 ei, ef, eg, eo;
        #pragma unroll
        for (int r = 0; r < 4; ++r) {
            ei[r] = exp2_fast(acc[0][r]);
            ef[r] = exp2_fast(acc[1][r]);
            eg[r] = exp2_fast(acc[2][r]);
            eo[r] = exp2_fast(acc[3][r]);
        }
        f32x4 Ai = vone + ei, Af = vone + ef, Ag = vone + eg, Ao = vone + eo;
        f32x4 P   = Ai * Ag;
        f32x4 PAF = P * Af;
        f32x4 rP;
        #pragma unroll
        for (int r = 0; r < 4; ++r) rP[r] = __builtin_amdgcn_rcpf(PAF[r]);
        f32x4 tg  = __builtin_elementwise_fma(vnC2, eg, vC2);   // C2*(1-eg), sign built in
        f32x4 num = __builtin_elementwise_fma(ct4, P, tg * Af);
        f32x4 cn  = num * rP;                                   // scaled cell state
        ct4 = cn;
        f32x4 mm = __builtin_elementwise_min(-cn, v40);         // exp2 arg, clamped (safe)
        f32x4 ec;
        #pragma unroll
        for (int r = 0; r < 4; ++r) ec[r] = exp2_fast(mm[r]);
        f32x4 tc  = vone - ec;                                  // sign built in
        f32x4 den = Ao * (vone + ec);
        f32x4 rden;
        #pragma unroll
        for (int r = 0; r < 4; ++r) rden[r] = __builtin_amdgcn_rcpf(den[r]);
        f32x4 hv = tc * rden;                                   // real-unit h

        // per-pair bf16 pack (HW RNE) + exact lo residuals (packed sub); 4x ds_write_b32
        unsigned* whi = reinterpret_cast<unsigned*>(&hbuf[wb][0][0][0]);
        unsigned* wlo = reinterpret_cast<unsigned*>(&hbuf[wb][1][0][0]);
        unsigned hi01, hi23, lo01, lo23;
        asm("v_cvt_pk_bf16_f32 %0, %1, %2" : "=v"(hi01) : "v"(hv[0]), "v"(hv[1]));
        whi[(woff >> 1) + 0] = hi01;
        asm("v_cvt_pk_bf16_f32 %0, %1, %2" : "=v"(hi23) : "v"(hv[2]), "v"(hv[3]));
        whi[(woff >> 1) + 1] = hi23;
        f32x4 hif = { ubits(hi01 << 16), ubits(hi01 & 0xffff0000u),
                      ubits(hi23 << 16), ubits(hi23 & 0xffff0000u) };
        f32x4 l4 = hv - hif;   // exact residuals (Sterbenz)
        asm("v_cvt_pk_bf16_f32 %0, %1, %2" : "=v"(lo01) : "v"(l4[0]), "v"(l4[1]));
        wlo[(woff >> 1) + 0] = lo01;
        asm("v_cvt_pk_bf16_f32 %0, %1, %2" : "=v"(lo23) : "v"(l4[2]), "v"(l4[3]));
        wlo[(woff >> 1) + 1] = lo23;

        __syncthreads();   // h(t+1) visible; also protects next step's overwrite of rb
    }

    // ---- final FC: out[b] = sum_k h[b][k]*W_fc[k] + b_fc  (h = buf 0 after t=511) ----
    if (tid < 16) {
        int b = tid;
        float s = b_fc[0];
        #pragma unroll 4
        for (int k = 0; k < 64; ++k) {
            float hv = bf2f(hbuf[0][0][b][k]) + bf2f(hbuf[0][1][b][k]);
            s += hv * W_fc[k];
        }
        out[b0 + b] = s;
    }
}

extern "C" void kernel_launch(void* const* d_in, const int* in_sizes, int n_in,
                              void* d_out, int out_size, void* d_ws, size_t ws_size,
                              hipStream_t stream) {
    const float* x    = (const float*)d_in[0];
    const float* W_ih = (const float*)d_in[1];
    const float* W_hh = (const float*)d_in[2];
    const float* b_ih = (const float*)d_in[3];
    const float* b_hh = (const float*)d_in[4];
    const float* W_fc = (const float*)d_in[5];
    const float* b_fc = (const float*)d_in[6];
    float* out = (float*)d_out;
    const int B = in_sizes[0] / T_STEPS;   // 4096
    lstm_persist<<<dim3(B / BT), dim3(256), 0, stream>>>(
        x, W_ih, W_hh, b_ih, b_hh, W_fc, b_fc, out);
}